// Round 12
// baseline (721.404 us; speedup 1.0000x reference)
//
#include <hip/hip_runtime.h>
#include <hip/hip_bf16.h>

#define BN_EPS 1e-5f

typedef short short8 __attribute__((ext_vector_type(8)));
typedef float f32x4  __attribute__((ext_vector_type(4)));
typedef unsigned int u32x2 __attribute__((ext_vector_type(2)));

__device__ inline float bf2f(short s) {
    unsigned u = ((unsigned)(unsigned short)s) << 16;
    return __builtin_bit_cast(float, u);
}
__device__ inline short f2bf(float f) {
    __hip_bfloat16 h = __float2bfloat16(f);
    return __builtin_bit_cast(short, h);
}
__device__ inline unsigned pack2(float a, float b) {
    return (unsigned)(unsigned short)f2bf(a) | ((unsigned)(unsigned short)f2bf(b) << 16);
}
__device__ inline f32x4 mfma16(short8 a, short8 b, f32x4 c) {
    return __builtin_amdgcn_mfma_f32_16x16x32_bf16(a, b, c, 0, 0, 0);
}

// ---------------------------------------------------------------------------
// Blocks 0..11: weight fragments (4 matrices). Blocks 12..: h2 embed.
__global__ __launch_bounds__(256) void prep_embed_kernel(
    const float* __restrict__ mW1, const float* __restrict__ mW2,
    const float* __restrict__ uW1, const float* __restrict__ uW2,
    short* __restrict__ w1f, short* __restrict__ w2f,
    short* __restrict__ nw1f, short* __restrict__ nw2f,
    const float* __restrict__ pos, const float* __restrict__ vel,
    const float* __restrict__ W, const float* __restrict__ b,
    short* __restrict__ h2, int N)
{
    if (blockIdx.x < 12) {
        int s = blockIdx.x * 256 + threadIdx.x;      // 0..3071
        const float* Wm; short* out; int base;
        if (s < 1024)      { Wm = mW1; out = w1f;  base = s; }
        else if (s < 1536) { Wm = mW2; out = w2f;  base = s - 1024; }
        else if (s < 2560) { Wm = uW1; out = nw1f; base = s - 1536; }
        else               { Wm = uW2; out = nw2f; base = s - 2560; }
        int lane = base & 63, cb = (base >> 6) & 3, t = base >> 8;
        int n  = cb * 16 + (lane & 15);
        int k0 = t * 32 + ((lane >> 4) * 8);
        short8 v;
#pragma unroll
        for (int j = 0; j < 8; ++j) v[j] = f2bf(Wm[(k0 + j) * 64 + n]);
        *(short8*)(out + (size_t)base * 8) = v;
    } else {
        int t = (blockIdx.x - 12) * 256 + threadIdx.x;
        if (t >= N * 64) return;
        int i = t >> 6, c = t & 63;
        float acc = b[c];
        acc = fmaf(pos[2 * i],     W[c],       acc);
        acc = fmaf(pos[2 * i + 1], W[64 + c],  acc);
        acc = fmaf(vel[2 * i],     W[128 + c], acc);
        acc = fmaf(vel[2 * i + 1], W[192 + c], acc);
        h2[t] = f2bf(acc);
    }
}

// ---------------------------------------------------------------------------
// Combined: dst histogram (all edges) + sampled BN1 raw stats via GEMM1.
__global__ __launch_bounds__(256) void hist_stats_kernel(
    const short* __restrict__ h2, const int* __restrict__ dst,
    const int* __restrict__ src, const short* __restrict__ w1f,
    int* __restrict__ cnt, float* __restrict__ statsOut, int E, int tstep)
{
    __shared__ float sred[512];
    const int lane = threadIdx.x & 63;
    const int wv   = threadIdx.x >> 6;
    const int m16  = lane & 15;
    const int quad = lane >> 4;
    short8 w1r[16];
#pragma unroll
    for (int s = 0; s < 16; ++s) w1r[s] = *(const short8*)(w1f + ((size_t)s * 64 + lane) * 8);

    // Part 1: histogram over all edges
    const int gtid   = blockIdx.x * blockDim.x + threadIdx.x;
    const int stride = gridDim.x * blockDim.x;
    for (int e = gtid; e < E; e += stride)
        atomicAdd(&cnt[dst[e]], 1);

    // Part 2: sampled GEMM1 stats (every tstep-th 16-edge tile)
    float s1[16], s2[16];
#pragma unroll
    for (int u = 0; u < 16; ++u) { s1[u] = 0.f; s2[u] = 0.f; }
    const int wid  = gtid >> 6;
    const int nw   = stride >> 6;
    const int neff = (E >> 4) / tstep;
    for (int ts = wid; ts < neff; ts += nw) {
        const int e  = ((ts * tstep) << 4) + m16;
        const int ra = dst[e], rb = src[e];
        const short* pa = h2 + (size_t)ra * 64;
        const short* pb = h2 + (size_t)rb * 64;
        short8 a0 = *(const short8*)(pa + quad * 8);
        short8 a1 = *(const short8*)(pa + 32 + quad * 8);
        short8 a2 = *(const short8*)(pb + quad * 8);
        short8 a3 = *(const short8*)(pb + 32 + quad * 8);
#pragma unroll
        for (int cb = 0; cb < 4; ++cb) {
            f32x4 c = {0.f, 0.f, 0.f, 0.f};
            c = mfma16(w1r[0 * 4 + cb], a0, c);
            c = mfma16(w1r[1 * 4 + cb], a1, c);
            c = mfma16(w1r[2 * 4 + cb], a2, c);
            c = mfma16(w1r[3 * 4 + cb], a3, c);
#pragma unroll
            for (int r = 0; r < 4; ++r) {
                float v = c[r];
                s1[cb * 4 + r] += v;
                s2[cb * 4 + r] += v * v;
            }
        }
    }
#pragma unroll
    for (int u = 0; u < 16; ++u) {
#pragma unroll
        for (int d = 1; d < 16; d <<= 1) {
            s1[u] += __shfl_xor(s1[u], d, 64);
            s2[u] += __shfl_xor(s2[u], d, 64);
        }
    }
    if (m16 == 0) {
#pragma unroll
        for (int u = 0; u < 16; ++u) {
            int ch = (u >> 2) * 16 + quad * 4 + (u & 3);
            sred[wv * 128 + ch]      = s1[u];
            sred[wv * 128 + 64 + ch] = s2[u];
        }
    }
    __syncthreads();
    if (threadIdx.x < 128) {
        float t = sred[threadIdx.x] + sred[128 + threadIdx.x] +
                  sred[256 + threadIdx.x] + sred[384 + threadIdx.x];
        atomicAdd(&statsOut[threadIdx.x], t);
    }
}

// ---------------------------------------------------------------------------
__global__ __launch_bounds__(256) void scan1_kernel(
    const int* __restrict__ cnt, int* __restrict__ off, int* __restrict__ bsum, int n)
{
    __shared__ int s[256];
    const int tid  = threadIdx.x;
    const int base = blockIdx.x * 1024 + tid * 4;
    int v0 = (base     < n) ? cnt[base]     : 0;
    int v1 = (base + 1 < n) ? cnt[base + 1] : 0;
    int v2 = (base + 2 < n) ? cnt[base + 2] : 0;
    int v3 = (base + 3 < n) ? cnt[base + 3] : 0;
    int tot = v0 + v1 + v2 + v3;
    s[tid] = tot;
    __syncthreads();
    for (int d = 1; d < 256; d <<= 1) {
        int y = (tid >= d) ? s[tid - d] : 0;
        __syncthreads();
        s[tid] += y;
        __syncthreads();
    }
    int excl = s[tid] - tot;
    if (base     < n) off[base]     = excl;
    if (base + 1 < n) off[base + 1] = excl + v0;
    if (base + 2 < n) off[base + 2] = excl + v0 + v1;
    if (base + 3 < n) off[base + 3] = excl + v0 + v1 + v2;
    if (tid == 255) bsum[blockIdx.x] = s[255];
}

__global__ void scan2_kernel(int* __restrict__ bsum, int nb)
{
    int lane = threadIdx.x;  // 64 threads
    int carry = 0;
    for (int base = 0; base < nb; base += 64) {
        int i = base + lane;
        int v = (i < nb) ? bsum[i] : 0;
        int x = v;
#pragma unroll
        for (int d = 1; d < 64; d <<= 1) {
            int y = __shfl_up(x, d, 64);
            if (lane >= d) x += y;
        }
        if (i < nb) bsum[i] = carry + x - v;
        carry += __shfl(x, 63, 64);
    }
}

__global__ __launch_bounds__(256) void scan3_kernel(
    int* __restrict__ off, int* __restrict__ cur, const int* __restrict__ bsum, int n, int E)
{
    int tid = blockIdx.x * blockDim.x + threadIdx.x;
    for (int i = tid; i < n; i += gridDim.x * blockDim.x) {
        int v = off[i] + bsum[i >> 10];
        off[i] = v;
        cur[i] = v;
    }
    if (tid == 0) off[n] = E;
}

// ---------------------------------------------------------------------------
// Fused edge pass (r8 structure): gather h2 rows, GEMM1, relu(bn1) via
// prologue-folded scale/shift, swizzled LDS transpose, GEMM2, y2 -> CSR slot
// (nontemporal store), bn2 raw stats. 1-ahead gather prefetch.
__global__ __launch_bounds__(256) void edge_fused_kernel(
    const short* __restrict__ h2,
    const int* __restrict__ dst, const int* __restrict__ src,
    const short* __restrict__ wf1, const short* __restrict__ wf2,
    const float* __restrict__ raw1, const float* __restrict__ g1v,
    const float* __restrict__ B1v, float invc1,
    float* __restrict__ statsOut, short* __restrict__ outp,
    int* __restrict__ cur, int E)
{
    extern __shared__ short xs[];
    const int lane = threadIdx.x & 63;
    const int wv   = threadIdx.x >> 6;
    const int m16  = lane & 15;
    const int quad = lane >> 4;
    const int swz  = (m16 & 7) << 1;
    short* lds = xs + wv * 1024;
    float* sred = (float*)(xs + 4096);

    short8 w1r[16];
#pragma unroll
    for (int s = 0; s < 16; ++s) w1r[s] = *(const short8*)(wf1 + ((size_t)s * 64 + lane) * 8);
    short8 w2r[8];
#pragma unroll
    for (int s = 0; s < 8; ++s) w2r[s] = *(const short8*)(wf2 + ((size_t)s * 64 + lane) * 8);
    float sc_m[16], sh_m[16];
#pragma unroll
    for (int u = 0; u < 16; ++u) {
        int ch = (u >> 2) * 16 + quad * 4 + (u & 3);
        float mu  = raw1[ch] * invc1;
        float var = fmaf(raw1[64 + ch], invc1, -mu * mu);
        float sc  = rsqrtf(var + BN_EPS) * g1v[ch];
        sc_m[u] = sc;
        sh_m[u] = fmaf(-mu, sc, B1v[ch]);
    }
    float s1[16], s2[16];
#pragma unroll
    for (int u = 0; u < 16; ++u) { s1[u] = 0.f; s2[u] = 0.f; }

    const int wid = (blockIdx.x * blockDim.x + threadIdx.x) >> 6;
    const int nw  = (gridDim.x * blockDim.x) >> 6;
    const int ntiles = E >> 4;

    int tile = wid;
    short8 a0, a1, a2, a3;
    int raC = 0;
    if (tile < ntiles) {
        const int e = (tile << 4) + m16;
        raC = dst[e];
        const int rb = src[e];
        const short* pa = h2 + (size_t)raC * 64;
        const short* pb = h2 + (size_t)rb * 64;
        a0 = *(const short8*)(pa + quad * 8);
        a1 = *(const short8*)(pa + 32 + quad * 8);
        a2 = *(const short8*)(pb + quad * 8);
        a3 = *(const short8*)(pb + 32 + quad * 8);
    }
    while (tile < ntiles) {
        const int nxt = tile + nw;
        short8 n0, n1, n2, n3;
        int raN = 0;
        if (nxt < ntiles) {                      // 1-ahead prefetch (r8 pattern)
            const int e = (nxt << 4) + m16;
            raN = dst[e];
            const int rb = src[e];
            const short* pa = h2 + (size_t)raN * 64;
            const short* pb = h2 + (size_t)rb * 64;
            n0 = *(const short8*)(pa + quad * 8);
            n1 = *(const short8*)(pa + 32 + quad * 8);
            n2 = *(const short8*)(pb + quad * 8);
            n3 = *(const short8*)(pb + 32 + quad * 8);
        }
        int s = 0;
        if (quad == 0) s = atomicAdd(&cur[raC], 1);
        const int orow = __shfl(s, m16, 64);
#pragma unroll
        for (int cb = 0; cb < 4; ++cb) {
            f32x4 c = {0.f, 0.f, 0.f, 0.f};
            c = mfma16(w1r[0 * 4 + cb], a0, c);
            c = mfma16(w1r[1 * 4 + cb], a1, c);
            c = mfma16(w1r[2 * 4 + cb], a2, c);
            c = mfma16(w1r[3 * 4 + cb], a3, c);
            float r0 = fmaxf(fmaf(c[0], sc_m[cb * 4 + 0], sh_m[cb * 4 + 0]), 0.f);
            float r1 = fmaxf(fmaf(c[1], sc_m[cb * 4 + 1], sh_m[cb * 4 + 1]), 0.f);
            float r2 = fmaxf(fmaf(c[2], sc_m[cb * 4 + 2], sh_m[cb * 4 + 2]), 0.f);
            float r3 = fmaxf(fmaf(c[3], sc_m[cb * 4 + 3], sh_m[cb * 4 + 3]), 0.f);
            u32x2 p = { pack2(r0, r1), pack2(r2, r3) };
            *(u32x2*)(lds + m16 * 64 + (((cb * 4 + quad) ^ swz) << 2)) = p;
        }
        __builtin_amdgcn_wave_barrier();
        short8 b0 = *(const short8*)(lds + m16 * 64 + ((((quad << 1)    ) ^ swz) << 2));
        short8 b1 = *(const short8*)(lds + m16 * 64 + (((8 + (quad << 1)) ^ swz) << 2));
        __builtin_amdgcn_wave_barrier();
#pragma unroll
        for (int cb = 0; cb < 4; ++cb) {
            f32x4 c = {0.f, 0.f, 0.f, 0.f};
            c = mfma16(w2r[0 * 4 + cb], b0, c);
            c = mfma16(w2r[1 * 4 + cb], b1, c);
#pragma unroll
            for (int r = 0; r < 4; ++r) {
                float v = c[r];
                s1[cb * 4 + r] += v;
                s2[cb * 4 + r] += v * v;
            }
            u32x2 p = { pack2(c[0], c[1]), pack2(c[2], c[3]) };
            __builtin_nontemporal_store(p,
                (u32x2*)(outp + (size_t)orow * 64 + cb * 16 + quad * 4));
        }
        a0 = n0; a1 = n1; a2 = n2; a3 = n3;
        raC = raN;
        tile = nxt;
    }
#pragma unroll
    for (int u = 0; u < 16; ++u) {
#pragma unroll
        for (int d = 1; d < 16; d <<= 1) {
            s1[u] += __shfl_xor(s1[u], d, 64);
            s2[u] += __shfl_xor(s2[u], d, 64);
        }
    }
    if (m16 == 0) {
#pragma unroll
        for (int u = 0; u < 16; ++u) {
            int ch = (u >> 2) * 16 + quad * 4 + (u & 3);
            sred[wv * 128 + ch]      = s1[u];
            sred[wv * 128 + 64 + ch] = s2[u];
        }
    }
    __syncthreads();
    if (threadIdx.x < 128) {
        float t = sred[threadIdx.x] + sred[128 + threadIdx.x] +
                  sred[256 + threadIdx.x] + sred[384 + threadIdx.x];
        atomicAdd(&statsOut[threadIdx.x], t);
    }
}

// ---------------------------------------------------------------------------
// Node 2-layer MLP (identity rows, bn finalize in prologue).
template <bool FUSE>
__global__ __launch_bounds__(256) void node_mfma_kernel(
    const short* __restrict__ ptrA, const short* __restrict__ ptrB,
    const short* __restrict__ wf1, const short* __restrict__ wf2,
    const float* __restrict__ rawIn, const float* __restrict__ gamma,
    const float* __restrict__ beta, float invc,
    float* __restrict__ statsOut, short* __restrict__ outp, int M)
{
    extern __shared__ short xs[];
    const int lane = threadIdx.x & 63;
    const int wv   = threadIdx.x >> 6;
    const int m16  = lane & 15;
    const int quad = lane >> 4;
    const int swz  = (m16 & 7) << 1;
    short* lds = xs + wv * 1024;
    float* sred = (float*)(xs + (FUSE ? 4096 : 0));

    short8 w1r[16];
#pragma unroll
    for (int s = 0; s < 16; ++s) w1r[s] = *(const short8*)(wf1 + ((size_t)s * 64 + lane) * 8);
    short8 w2r[8];
    float sc_m[16], sh_m[16];
    if constexpr (FUSE) {
#pragma unroll
        for (int s = 0; s < 8; ++s) w2r[s] = *(const short8*)(wf2 + ((size_t)s * 64 + lane) * 8);
#pragma unroll
        for (int u = 0; u < 16; ++u) {
            int ch = (u >> 2) * 16 + quad * 4 + (u & 3);
            float mu  = rawIn[ch] * invc;
            float var = fmaf(rawIn[64 + ch], invc, -mu * mu);
            float sc  = rsqrtf(var + BN_EPS) * gamma[ch];
            sc_m[u] = sc;
            sh_m[u] = fmaf(-mu, sc, beta[ch]);
        }
    }
    float s1[16], s2[16];
#pragma unroll
    for (int u = 0; u < 16; ++u) { s1[u] = 0.f; s2[u] = 0.f; }

    const int wid = (blockIdx.x * blockDim.x + threadIdx.x) >> 6;
    const int nw  = (gridDim.x * blockDim.x) >> 6;
    const int ntiles = M >> 4;
    for (int tile = wid; tile < ntiles; tile += nw) {
        const int i = (tile << 4) + m16;
        const short* pa = ptrA + (size_t)i * 64;
        const short* pb = ptrB + (size_t)i * 64;
        short8 a0 = *(const short8*)(pa + quad * 8);
        short8 a1 = *(const short8*)(pa + 32 + quad * 8);
        short8 a2 = *(const short8*)(pb + quad * 8);
        short8 a3 = *(const short8*)(pb + 32 + quad * 8);
#pragma unroll
        for (int cb = 0; cb < 4; ++cb) {
            f32x4 c = {0.f, 0.f, 0.f, 0.f};
            c = mfma16(w1r[0 * 4 + cb], a0, c);
            c = mfma16(w1r[1 * 4 + cb], a1, c);
            c = mfma16(w1r[2 * 4 + cb], a2, c);
            c = mfma16(w1r[3 * 4 + cb], a3, c);
            if constexpr (!FUSE) {
#pragma unroll
                for (int r = 0; r < 4; ++r) {
                    float v = c[r];
                    s1[cb * 4 + r] += v;
                    s2[cb * 4 + r] += v * v;
                }
            } else {
                float r0 = fmaxf(fmaf(c[0], sc_m[cb * 4 + 0], sh_m[cb * 4 + 0]), 0.f);
                float r1 = fmaxf(fmaf(c[1], sc_m[cb * 4 + 1], sh_m[cb * 4 + 1]), 0.f);
                float r2 = fmaxf(fmaf(c[2], sc_m[cb * 4 + 2], sh_m[cb * 4 + 2]), 0.f);
                float r3 = fmaxf(fmaf(c[3], sc_m[cb * 4 + 3], sh_m[cb * 4 + 3]), 0.f);
                u32x2 p = { pack2(r0, r1), pack2(r2, r3) };
                *(u32x2*)(lds + m16 * 64 + (((cb * 4 + quad) ^ swz) << 2)) = p;
            }
        }
        if constexpr (FUSE) {
            __builtin_amdgcn_wave_barrier();
            short8 b0 = *(const short8*)(lds + m16 * 64 + ((((quad << 1)    ) ^ swz) << 2));
            short8 b1 = *(const short8*)(lds + m16 * 64 + (((8 + (quad << 1)) ^ swz) << 2));
            __builtin_amdgcn_wave_barrier();
#pragma unroll
            for (int cb = 0; cb < 4; ++cb) {
                f32x4 c = {0.f, 0.f, 0.f, 0.f};
                c = mfma16(w2r[0 * 4 + cb], b0, c);
                c = mfma16(w2r[1 * 4 + cb], b1, c);
#pragma unroll
                for (int r = 0; r < 4; ++r) {
                    float v = c[r];
                    s1[cb * 4 + r] += v;
                    s2[cb * 4 + r] += v * v;
                }
                u32x2 p = { pack2(c[0], c[1]), pack2(c[2], c[3]) };
                *(u32x2*)(outp + (size_t)i * 64 + cb * 16 + quad * 4) = p;
            }
        }
    }
#pragma unroll
    for (int u = 0; u < 16; ++u) {
#pragma unroll
        for (int d = 1; d < 16; d <<= 1) {
            s1[u] += __shfl_xor(s1[u], d, 64);
            s2[u] += __shfl_xor(s2[u], d, 64);
        }
    }
    if (m16 == 0) {
#pragma unroll
        for (int u = 0; u < 16; ++u) {
            int ch = (u >> 2) * 16 + quad * 4 + (u & 3);
            sred[wv * 128 + ch]      = s1[u];
            sred[wv * 128 + 64 + ch] = s2[u];
        }
    }
    __syncthreads();
    if (threadIdx.x < 128) {
        float t = sred[threadIdx.x] + sred[128 + threadIdx.x] +
                  sred[256 + threadIdx.x] + sred[384 + threadIdx.x];
        atomicAdd(&statsOut[threadIdx.x], t);
    }
}

// ---------------------------------------------------------------------------
// aggr2[i][:] = bf16( sum over CSR slots of relu(bn2(y2p[k][:])) )
__global__ __launch_bounds__(256) void agg_gather_kernel(
    const short* __restrict__ y2p, const int* __restrict__ off,
    const float* __restrict__ raw, const float* __restrict__ gamma,
    const float* __restrict__ beta, float invc,
    short* __restrict__ aggr2, int N)
{
    const int lane = threadIdx.x & 63;
    const int r    = lane >> 5;
    const int c2   = lane & 31;
    const int c0   = 2 * c2;
    float mu0  = raw[c0] * invc;
    float var0 = fmaf(raw[64 + c0], invc, -mu0 * mu0);
    float sa   = rsqrtf(var0 + BN_EPS) * gamma[c0];
    float ha   = fmaf(-mu0, sa, beta[c0]);
    float mu1  = raw[c0 + 1] * invc;
    float var1 = fmaf(raw[64 + c0 + 1], invc, -mu1 * mu1);
    float sb   = rsqrtf(var1 + BN_EPS) * gamma[c0 + 1];
    float hb   = fmaf(-mu1, sb, beta[c0 + 1]);
    const int wid = (blockIdx.x * blockDim.x + threadIdx.x) >> 6;
    const int nw  = (gridDim.x * blockDim.x) >> 6;
    for (int i = wid; i < N; i += nw) {
        int a = off[i], b = off[i + 1];
        float acc0 = 0.f, acc1 = 0.f;
        int k = a;
        for (; k + 2 <= b; k += 2) {
            unsigned u = __builtin_nontemporal_load(
                (const unsigned*)(y2p + (size_t)(k + r) * 64 + c0));
            acc0 += fmaxf(fmaf(bf2f((short)(u & 0xffff)), sa, ha), 0.f);
            acc1 += fmaxf(fmaf(bf2f((short)(u >> 16)),    sb, hb), 0.f);
        }
        if (k < b && r == 0) {
            unsigned u = __builtin_nontemporal_load(
                (const unsigned*)(y2p + (size_t)k * 64 + c0));
            acc0 += fmaxf(fmaf(bf2f((short)(u & 0xffff)), sa, ha), 0.f);
            acc1 += fmaxf(fmaf(bf2f((short)(u >> 16)),    sb, hb), 0.f);
        }
        acc0 += __shfl_xor(acc0, 32, 64);
        acc1 += __shfl_xor(acc1, 32, 64);
        if (lane < 32)
            *(unsigned*)(aggr2 + (size_t)i * 64 + c0) = pack2(acc0, acc1);
    }
}

// ---------------------------------------------------------------------------
__global__ __launch_bounds__(256) void pred_kernel(
    const short* __restrict__ z2, const float* __restrict__ raw,
    const float* __restrict__ gamma, const float* __restrict__ beta, float invc,
    const float* __restrict__ Wp, const float* __restrict__ bp,
    float* __restrict__ out, int Nn)
{
    const int lane = threadIdx.x & 63;
    float mu  = raw[lane] * invc;
    float var = fmaf(raw[64 + lane], invc, -mu * mu);
    float sc  = rsqrtf(var + BN_EPS) * gamma[lane];
    float sh  = fmaf(-mu, sc, beta[lane]);
    const float wc = Wp[lane];
    const float bb = bp[0];
    const int wid = (blockIdx.x * blockDim.x + threadIdx.x) >> 6;
    const int nw  = (gridDim.x * blockDim.x) >> 6;
    for (int i = wid; i < Nn; i += nw) {
        float v = bf2f(z2[(size_t)i * 64 + lane]);
        float p = fmaxf(fmaf(v, sc, sh), 0.f) * wc;
#pragma unroll
        for (int off = 32; off > 0; off >>= 1) p += __shfl_xor(p, off, 64);
        if (lane == 0) out[i] = p + bb;
    }
}

// ---------------------------------------------------------------------------
extern "C" void kernel_launch(void* const* d_in, const int* in_sizes, int n_in,
                              void* d_out, int out_size, void* d_ws, size_t ws_size,
                              hipStream_t stream)
{
    const float* pos  = (const float*)d_in[0];
    const float* vel  = (const float*)d_in[1];
    const int*   eidx = (const int*)d_in[2];
    const float* W_in = (const float*)d_in[3];
    const float* b_in = (const float*)d_in[4];
    const float* mW1  = (const float*)d_in[5];
    const float* mg1  = (const float*)d_in[7];
    const float* mB1  = (const float*)d_in[8];
    const float* mW2  = (const float*)d_in[9];
    const float* mg2  = (const float*)d_in[11];
    const float* mB2  = (const float*)d_in[12];
    const float* uW1  = (const float*)d_in[13];
    const float* ug1  = (const float*)d_in[15];
    const float* uB1  = (const float*)d_in[16];
    const float* uW2  = (const float*)d_in[17];
    const float* ug2  = (const float*)d_in[19];
    const float* uB2  = (const float*)d_in[20];
    const float* Wp   = (const float*)d_in[21];
    const float* bp   = (const float*)d_in[22];
    // NOTE: mb1/mb2/ub1/ub2 cancel exactly through batch-stat BN.

    const int N = in_sizes[0] / 2;
    const int E = in_sizes[2] / 2;
    const int* src = eidx;       // edge_index[0] = source j
    const int* dst = eidx + E;   // edge_index[1] = dest   i (aggregation target)

    // workspace layout (~244.5 MB — proven r5–r9 footprint)
    float* ws    = (float*)d_ws;
    float* stats = ws;                         // 4 x 128 raw (sum, sumsq)
    int*   cnt   = (int*)(ws + 512);           // N
    int*   off   = cnt + N;                    // N+4
    int*   cur   = off + N + 4;                // N
    int*   bsum  = cur + N;                    // 1024
    short* w1f   = (short*)(bsum + 1024);      // 8192
    short* w2f   = w1f + 8192;                 // 4096
    short* nw1f  = w2f + 4096;                 // 8192
    short* nw2f  = nw1f + 8192;                // 4096
    short* h2    = nw2f + 4096;                // N*64 bf16
    short* aggr2 = h2 + (size_t)N * 64;        // N*64 bf16
    short* z2    = aggr2 + (size_t)N * 64;     // N*64 bf16
    short* y2p   = z2 + (size_t)N * 64;        // E*64 bf16 (CSR slot order)
    float* out   = (float*)d_out;

    const int NB = (N + 1023) / 1024;
    const int FUSE_LDS = 4 * 2048 + 2048;
    const int STAT_LDS = 2048;
    const int TSTEP = 8;
    const int nsamp = ((E >> 4) / TSTEP) << 4;

    hipMemsetAsync(stats, 0, 512 * sizeof(float) + (size_t)N * sizeof(int), stream);

    prep_embed_kernel<<<12 + (N * 64 + 255) / 256, 256, 0, stream>>>(
        mW1, mW2, uW1, uW2, w1f, w2f, nw1f, nw2f,
        pos, vel, W_in, b_in, h2, N);

    hist_stats_kernel<<<1024, 256, 0, stream>>>(
        h2, dst, src, w1f, cnt, stats + 0, E, TSTEP);

    scan1_kernel<<<NB, 256, 0, stream>>>(cnt, off, bsum, N);
    scan2_kernel<<<1, 64, 0, stream>>>(bsum, NB);
    scan3_kernel<<<512, 256, 0, stream>>>(off, cur, bsum, N, E);

    edge_fused_kernel<<<2048, 256, FUSE_LDS, stream>>>(
        h2, dst, src, w1f, w2f, stats + 0, mg1, mB1, 1.0f / (float)nsamp,
        stats + 128, y2p, cur, E);

    agg_gather_kernel<<<2048, 256, 0, stream>>>(
        y2p, off, stats + 128, mg2, mB2, 1.0f / (float)E, aggr2, N);

    node_mfma_kernel<false><<<1024, 256, STAT_LDS, stream>>>(
        h2, aggr2, nw1f, nullptr, nullptr, nullptr, nullptr, 0.f,
        stats + 256, nullptr, N);
    node_mfma_kernel<true><<<1024, 256, FUSE_LDS, stream>>>(
        h2, aggr2, nw1f, nw2f, stats + 256, ug1, uB1, 1.0f / (float)N,
        stats + 384, z2, N);

    pred_kernel<<<512, 256, 0, stream>>>(
        z2, stats + 384, ug2, uB2, 1.0f / (float)N, Wp, bp, out, N);
}

// Round 13
// 590.798 us; speedup vs baseline: 1.2211x; 1.2211x over previous
//
#include <hip/hip_runtime.h>
#include <hip/hip_bf16.h>

#define BN_EPS 1e-5f

typedef short short8 __attribute__((ext_vector_type(8)));
typedef float f32x4  __attribute__((ext_vector_type(4)));
typedef unsigned int u32x2 __attribute__((ext_vector_type(2)));

__device__ inline float bf2f(short s) {
    unsigned u = ((unsigned)(unsigned short)s) << 16;
    return __builtin_bit_cast(float, u);
}
__device__ inline short f2bf(float f) {
    __hip_bfloat16 h = __float2bfloat16(f);
    return __builtin_bit_cast(short, h);
}
__device__ inline unsigned pack2(float a, float b) {
    return (unsigned)(unsigned short)f2bf(a) | ((unsigned)(unsigned short)f2bf(b) << 16);
}
__device__ inline f32x4 mfma16(short8 a, short8 b, f32x4 c) {
    return __builtin_amdgcn_mfma_f32_16x16x32_bf16(a, b, c, 0, 0, 0);
}

// ---------------------------------------------------------------------------
// Blocks 0..11: weight fragments (4 matrices). Blocks 12..: h2 embed.
__global__ __launch_bounds__(256) void prep_embed_kernel(
    const float* __restrict__ mW1, const float* __restrict__ mW2,
    const float* __restrict__ uW1, const float* __restrict__ uW2,
    short* __restrict__ w1f, short* __restrict__ w2f,
    short* __restrict__ nw1f, short* __restrict__ nw2f,
    const float* __restrict__ pos, const float* __restrict__ vel,
    const float* __restrict__ W, const float* __restrict__ b,
    short* __restrict__ h2, int N)
{
    if (blockIdx.x < 12) {
        int s = blockIdx.x * 256 + threadIdx.x;      // 0..3071
        const float* Wm; short* out; int base;
        if (s < 1024)      { Wm = mW1; out = w1f;  base = s; }
        else if (s < 1536) { Wm = mW2; out = w2f;  base = s - 1024; }
        else if (s < 2560) { Wm = uW1; out = nw1f; base = s - 1536; }
        else               { Wm = uW2; out = nw2f; base = s - 2560; }
        int lane = base & 63, cb = (base >> 6) & 3, t = base >> 8;
        int n  = cb * 16 + (lane & 15);
        int k0 = t * 32 + ((lane >> 4) * 8);
        short8 v;
#pragma unroll
        for (int j = 0; j < 8; ++j) v[j] = f2bf(Wm[(k0 + j) * 64 + n]);
        *(short8*)(out + (size_t)base * 8) = v;
    } else {
        int t = (blockIdx.x - 12) * 256 + threadIdx.x;
        if (t >= N * 64) return;
        int i = t >> 6, c = t & 63;
        float acc = b[c];
        acc = fmaf(pos[2 * i],     W[c],       acc);
        acc = fmaf(pos[2 * i + 1], W[64 + c],  acc);
        acc = fmaf(vel[2 * i],     W[128 + c], acc);
        acc = fmaf(vel[2 * i + 1], W[192 + c], acc);
        h2[t] = f2bf(acc);
    }
}

// ---------------------------------------------------------------------------
// Combined: dst histogram (all edges) + sampled BN1 raw stats via GEMM1.
__global__ __launch_bounds__(256) void hist_stats_kernel(
    const short* __restrict__ h2, const int* __restrict__ dst,
    const int* __restrict__ src, const short* __restrict__ w1f,
    int* __restrict__ cnt, float* __restrict__ statsOut, int E, int tstep)
{
    __shared__ float sred[512];
    const int lane = threadIdx.x & 63;
    const int wv   = threadIdx.x >> 6;
    const int m16  = lane & 15;
    const int quad = lane >> 4;
    short8 w1r[16];
#pragma unroll
    for (int s = 0; s < 16; ++s) w1r[s] = *(const short8*)(w1f + ((size_t)s * 64 + lane) * 8);

    // Part 1: histogram over all edges
    const int gtid   = blockIdx.x * blockDim.x + threadIdx.x;
    const int stride = gridDim.x * blockDim.x;
    for (int e = gtid; e < E; e += stride)
        atomicAdd(&cnt[dst[e]], 1);

    // Part 2: sampled GEMM1 stats (every tstep-th 16-edge tile)
    float s1[16], s2[16];
#pragma unroll
    for (int u = 0; u < 16; ++u) { s1[u] = 0.f; s2[u] = 0.f; }
    const int wid  = gtid >> 6;
    const int nw   = stride >> 6;
    const int neff = (E >> 4) / tstep;
    for (int ts = wid; ts < neff; ts += nw) {
        const int e  = ((ts * tstep) << 4) + m16;
        const int ra = dst[e], rb = src[e];
        const short* pa = h2 + (size_t)ra * 64;
        const short* pb = h2 + (size_t)rb * 64;
        short8 a0 = *(const short8*)(pa + quad * 8);
        short8 a1 = *(const short8*)(pa + 32 + quad * 8);
        short8 a2 = *(const short8*)(pb + quad * 8);
        short8 a3 = *(const short8*)(pb + 32 + quad * 8);
#pragma unroll
        for (int cb = 0; cb < 4; ++cb) {
            f32x4 c = {0.f, 0.f, 0.f, 0.f};
            c = mfma16(w1r[0 * 4 + cb], a0, c);
            c = mfma16(w1r[1 * 4 + cb], a1, c);
            c = mfma16(w1r[2 * 4 + cb], a2, c);
            c = mfma16(w1r[3 * 4 + cb], a3, c);
#pragma unroll
            for (int r = 0; r < 4; ++r) {
                float v = c[r];
                s1[cb * 4 + r] += v;
                s2[cb * 4 + r] += v * v;
            }
        }
    }
#pragma unroll
    for (int u = 0; u < 16; ++u) {
#pragma unroll
        for (int d = 1; d < 16; d <<= 1) {
            s1[u] += __shfl_xor(s1[u], d, 64);
            s2[u] += __shfl_xor(s2[u], d, 64);
        }
    }
    if (m16 == 0) {
#pragma unroll
        for (int u = 0; u < 16; ++u) {
            int ch = (u >> 2) * 16 + quad * 4 + (u & 3);
            sred[wv * 128 + ch]      = s1[u];
            sred[wv * 128 + 64 + ch] = s2[u];
        }
    }
    __syncthreads();
    if (threadIdx.x < 128) {
        float t = sred[threadIdx.x] + sred[128 + threadIdx.x] +
                  sred[256 + threadIdx.x] + sred[384 + threadIdx.x];
        atomicAdd(&statsOut[threadIdx.x], t);
    }
}

// ---------------------------------------------------------------------------
__global__ __launch_bounds__(256) void scan1_kernel(
    const int* __restrict__ cnt, int* __restrict__ off, int* __restrict__ bsum, int n)
{
    __shared__ int s[256];
    const int tid  = threadIdx.x;
    const int base = blockIdx.x * 1024 + tid * 4;
    int v0 = (base     < n) ? cnt[base]     : 0;
    int v1 = (base + 1 < n) ? cnt[base + 1] : 0;
    int v2 = (base + 2 < n) ? cnt[base + 2] : 0;
    int v3 = (base + 3 < n) ? cnt[base + 3] : 0;
    int tot = v0 + v1 + v2 + v3;
    s[tid] = tot;
    __syncthreads();
    for (int d = 1; d < 256; d <<= 1) {
        int y = (tid >= d) ? s[tid - d] : 0;
        __syncthreads();
        s[tid] += y;
        __syncthreads();
    }
    int excl = s[tid] - tot;
    if (base     < n) off[base]     = excl;
    if (base + 1 < n) off[base + 1] = excl + v0;
    if (base + 2 < n) off[base + 2] = excl + v0 + v1;
    if (base + 3 < n) off[base + 3] = excl + v0 + v1 + v2;
    if (tid == 255) bsum[blockIdx.x] = s[255];
}

__global__ void scan2_kernel(int* __restrict__ bsum, int nb)
{
    int lane = threadIdx.x;  // 64 threads
    int carry = 0;
    for (int base = 0; base < nb; base += 64) {
        int i = base + lane;
        int v = (i < nb) ? bsum[i] : 0;
        int x = v;
#pragma unroll
        for (int d = 1; d < 64; d <<= 1) {
            int y = __shfl_up(x, d, 64);
            if (lane >= d) x += y;
        }
        if (i < nb) bsum[i] = carry + x - v;
        carry += __shfl(x, 63, 64);
    }
}

__global__ __launch_bounds__(256) void scan3_kernel(
    int* __restrict__ off, int* __restrict__ cur, const int* __restrict__ bsum, int n, int E)
{
    int tid = blockIdx.x * blockDim.x + threadIdx.x;
    for (int i = tid; i < n; i += gridDim.x * blockDim.x) {
        int v = off[i] + bsum[i >> 10];
        off[i] = v;
        cur[i] = v;
    }
    if (tid == 0) off[n] = E;
}

// ---------------------------------------------------------------------------
// Fused edge pass (r8 structure): gather h2 rows, GEMM1, relu(bn1) via
// prologue-folded scale/shift, swizzled LDS transpose, GEMM2, y2 -> CSR slot
// (PLAIN store — NT on scattered partial lines caused 2x write amplification,
// r12 post-mortem), bn2 raw stats. 1-ahead gather prefetch.
__global__ __launch_bounds__(256) void edge_fused_kernel(
    const short* __restrict__ h2,
    const int* __restrict__ dst, const int* __restrict__ src,
    const short* __restrict__ wf1, const short* __restrict__ wf2,
    const float* __restrict__ raw1, const float* __restrict__ g1v,
    const float* __restrict__ B1v, float invc1,
    float* __restrict__ statsOut, short* __restrict__ outp,
    int* __restrict__ cur, int E)
{
    extern __shared__ short xs[];
    const int lane = threadIdx.x & 63;
    const int wv   = threadIdx.x >> 6;
    const int m16  = lane & 15;
    const int quad = lane >> 4;
    const int swz  = (m16 & 7) << 1;
    short* lds = xs + wv * 1024;
    float* sred = (float*)(xs + 4096);

    short8 w1r[16];
#pragma unroll
    for (int s = 0; s < 16; ++s) w1r[s] = *(const short8*)(wf1 + ((size_t)s * 64 + lane) * 8);
    short8 w2r[8];
#pragma unroll
    for (int s = 0; s < 8; ++s) w2r[s] = *(const short8*)(wf2 + ((size_t)s * 64 + lane) * 8);
    float sc_m[16], sh_m[16];
#pragma unroll
    for (int u = 0; u < 16; ++u) {
        int ch = (u >> 2) * 16 + quad * 4 + (u & 3);
        float mu  = raw1[ch] * invc1;
        float var = fmaf(raw1[64 + ch], invc1, -mu * mu);
        float sc  = rsqrtf(var + BN_EPS) * g1v[ch];
        sc_m[u] = sc;
        sh_m[u] = fmaf(-mu, sc, B1v[ch]);
    }
    float s1[16], s2[16];
#pragma unroll
    for (int u = 0; u < 16; ++u) { s1[u] = 0.f; s2[u] = 0.f; }

    const int wid = (blockIdx.x * blockDim.x + threadIdx.x) >> 6;
    const int nw  = (gridDim.x * blockDim.x) >> 6;
    const int ntiles = E >> 4;

    int tile = wid;
    short8 a0, a1, a2, a3;
    int raC = 0;
    if (tile < ntiles) {
        const int e = (tile << 4) + m16;
        raC = dst[e];
        const int rb = src[e];
        const short* pa = h2 + (size_t)raC * 64;
        const short* pb = h2 + (size_t)rb * 64;
        a0 = *(const short8*)(pa + quad * 8);
        a1 = *(const short8*)(pa + 32 + quad * 8);
        a2 = *(const short8*)(pb + quad * 8);
        a3 = *(const short8*)(pb + 32 + quad * 8);
    }
    while (tile < ntiles) {
        const int nxt = tile + nw;
        short8 n0, n1, n2, n3;
        int raN = 0;
        if (nxt < ntiles) {                      // 1-ahead prefetch (r8 pattern)
            const int e = (nxt << 4) + m16;
            raN = dst[e];
            const int rb = src[e];
            const short* pa = h2 + (size_t)raN * 64;
            const short* pb = h2 + (size_t)rb * 64;
            n0 = *(const short8*)(pa + quad * 8);
            n1 = *(const short8*)(pa + 32 + quad * 8);
            n2 = *(const short8*)(pb + quad * 8);
            n3 = *(const short8*)(pb + 32 + quad * 8);
        }
        int s = 0;
        if (quad == 0) s = atomicAdd(&cur[raC], 1);
        const int orow = __shfl(s, m16, 64);
#pragma unroll
        for (int cb = 0; cb < 4; ++cb) {
            f32x4 c = {0.f, 0.f, 0.f, 0.f};
            c = mfma16(w1r[0 * 4 + cb], a0, c);
            c = mfma16(w1r[1 * 4 + cb], a1, c);
            c = mfma16(w1r[2 * 4 + cb], a2, c);
            c = mfma16(w1r[3 * 4 + cb], a3, c);
            float r0 = fmaxf(fmaf(c[0], sc_m[cb * 4 + 0], sh_m[cb * 4 + 0]), 0.f);
            float r1 = fmaxf(fmaf(c[1], sc_m[cb * 4 + 1], sh_m[cb * 4 + 1]), 0.f);
            float r2 = fmaxf(fmaf(c[2], sc_m[cb * 4 + 2], sh_m[cb * 4 + 2]), 0.f);
            float r3 = fmaxf(fmaf(c[3], sc_m[cb * 4 + 3], sh_m[cb * 4 + 3]), 0.f);
            u32x2 p = { pack2(r0, r1), pack2(r2, r3) };
            *(u32x2*)(lds + m16 * 64 + (((cb * 4 + quad) ^ swz) << 2)) = p;
        }
        __builtin_amdgcn_wave_barrier();
        short8 b0 = *(const short8*)(lds + m16 * 64 + ((((quad << 1)    ) ^ swz) << 2));
        short8 b1 = *(const short8*)(lds + m16 * 64 + (((8 + (quad << 1)) ^ swz) << 2));
        __builtin_amdgcn_wave_barrier();
#pragma unroll
        for (int cb = 0; cb < 4; ++cb) {
            f32x4 c = {0.f, 0.f, 0.f, 0.f};
            c = mfma16(w2r[0 * 4 + cb], b0, c);
            c = mfma16(w2r[1 * 4 + cb], b1, c);
#pragma unroll
            for (int r = 0; r < 4; ++r) {
                float v = c[r];
                s1[cb * 4 + r] += v;
                s2[cb * 4 + r] += v * v;
            }
            u32x2 p = { pack2(c[0], c[1]), pack2(c[2], c[3]) };
            *(u32x2*)(outp + (size_t)orow * 64 + cb * 16 + quad * 4) = p;
        }
        a0 = n0; a1 = n1; a2 = n2; a3 = n3;
        raC = raN;
        tile = nxt;
    }
#pragma unroll
    for (int u = 0; u < 16; ++u) {
#pragma unroll
        for (int d = 1; d < 16; d <<= 1) {
            s1[u] += __shfl_xor(s1[u], d, 64);
            s2[u] += __shfl_xor(s2[u], d, 64);
        }
    }
    if (m16 == 0) {
#pragma unroll
        for (int u = 0; u < 16; ++u) {
            int ch = (u >> 2) * 16 + quad * 4 + (u & 3);
            sred[wv * 128 + ch]      = s1[u];
            sred[wv * 128 + 64 + ch] = s2[u];
        }
    }
    __syncthreads();
    if (threadIdx.x < 128) {
        float t = sred[threadIdx.x] + sred[128 + threadIdx.x] +
                  sred[256 + threadIdx.x] + sred[384 + threadIdx.x];
        atomicAdd(&statsOut[threadIdx.x], t);
    }
}

// ---------------------------------------------------------------------------
// Node 2-layer MLP (identity rows, bn finalize in prologue).
template <bool FUSE>
__global__ __launch_bounds__(256) void node_mfma_kernel(
    const short* __restrict__ ptrA, const short* __restrict__ ptrB,
    const short* __restrict__ wf1, const short* __restrict__ wf2,
    const float* __restrict__ rawIn, const float* __restrict__ gamma,
    const float* __restrict__ beta, float invc,
    float* __restrict__ statsOut, short* __restrict__ outp, int M)
{
    extern __shared__ short xs[];
    const int lane = threadIdx.x & 63;
    const int wv   = threadIdx.x >> 6;
    const int m16  = lane & 15;
    const int quad = lane >> 4;
    const int swz  = (m16 & 7) << 1;
    short* lds = xs + wv * 1024;
    float* sred = (float*)(xs + (FUSE ? 4096 : 0));

    short8 w1r[16];
#pragma unroll
    for (int s = 0; s < 16; ++s) w1r[s] = *(const short8*)(wf1 + ((size_t)s * 64 + lane) * 8);
    short8 w2r[8];
    float sc_m[16], sh_m[16];
    if constexpr (FUSE) {
#pragma unroll
        for (int s = 0; s < 8; ++s) w2r[s] = *(const short8*)(wf2 + ((size_t)s * 64 + lane) * 8);
#pragma unroll
        for (int u = 0; u < 16; ++u) {
            int ch = (u >> 2) * 16 + quad * 4 + (u & 3);
            float mu  = rawIn[ch] * invc;
            float var = fmaf(rawIn[64 + ch], invc, -mu * mu);
            float sc  = rsqrtf(var + BN_EPS) * gamma[ch];
            sc_m[u] = sc;
            sh_m[u] = fmaf(-mu, sc, beta[ch]);
        }
    }
    float s1[16], s2[16];
#pragma unroll
    for (int u = 0; u < 16; ++u) { s1[u] = 0.f; s2[u] = 0.f; }

    const int wid = (blockIdx.x * blockDim.x + threadIdx.x) >> 6;
    const int nw  = (gridDim.x * blockDim.x) >> 6;
    const int ntiles = M >> 4;
    for (int tile = wid; tile < ntiles; tile += nw) {
        const int i = (tile << 4) + m16;
        const short* pa = ptrA + (size_t)i * 64;
        const short* pb = ptrB + (size_t)i * 64;
        short8 a0 = *(const short8*)(pa + quad * 8);
        short8 a1 = *(const short8*)(pa + 32 + quad * 8);
        short8 a2 = *(const short8*)(pb + quad * 8);
        short8 a3 = *(const short8*)(pb + 32 + quad * 8);
#pragma unroll
        for (int cb = 0; cb < 4; ++cb) {
            f32x4 c = {0.f, 0.f, 0.f, 0.f};
            c = mfma16(w1r[0 * 4 + cb], a0, c);
            c = mfma16(w1r[1 * 4 + cb], a1, c);
            c = mfma16(w1r[2 * 4 + cb], a2, c);
            c = mfma16(w1r[3 * 4 + cb], a3, c);
            if constexpr (!FUSE) {
#pragma unroll
                for (int r = 0; r < 4; ++r) {
                    float v = c[r];
                    s1[cb * 4 + r] += v;
                    s2[cb * 4 + r] += v * v;
                }
            } else {
                float r0 = fmaxf(fmaf(c[0], sc_m[cb * 4 + 0], sh_m[cb * 4 + 0]), 0.f);
                float r1 = fmaxf(fmaf(c[1], sc_m[cb * 4 + 1], sh_m[cb * 4 + 1]), 0.f);
                float r2 = fmaxf(fmaf(c[2], sc_m[cb * 4 + 2], sh_m[cb * 4 + 2]), 0.f);
                float r3 = fmaxf(fmaf(c[3], sc_m[cb * 4 + 3], sh_m[cb * 4 + 3]), 0.f);
                u32x2 p = { pack2(r0, r1), pack2(r2, r3) };
                *(u32x2*)(lds + m16 * 64 + (((cb * 4 + quad) ^ swz) << 2)) = p;
            }
        }
        if constexpr (FUSE) {
            __builtin_amdgcn_wave_barrier();
            short8 b0 = *(const short8*)(lds + m16 * 64 + ((((quad << 1)    ) ^ swz) << 2));
            short8 b1 = *(const short8*)(lds + m16 * 64 + (((8 + (quad << 1)) ^ swz) << 2));
            __builtin_amdgcn_wave_barrier();
#pragma unroll
            for (int cb = 0; cb < 4; ++cb) {
                f32x4 c = {0.f, 0.f, 0.f, 0.f};
                c = mfma16(w2r[0 * 4 + cb], b0, c);
                c = mfma16(w2r[1 * 4 + cb], b1, c);
#pragma unroll
                for (int r = 0; r < 4; ++r) {
                    float v = c[r];
                    s1[cb * 4 + r] += v;
                    s2[cb * 4 + r] += v * v;
                }
                u32x2 p = { pack2(c[0], c[1]), pack2(c[2], c[3]) };
                *(u32x2*)(outp + (size_t)i * 64 + cb * 16 + quad * 4) = p;
            }
        }
    }
#pragma unroll
    for (int u = 0; u < 16; ++u) {
#pragma unroll
        for (int d = 1; d < 16; d <<= 1) {
            s1[u] += __shfl_xor(s1[u], d, 64);
            s2[u] += __shfl_xor(s2[u], d, 64);
        }
    }
    if (m16 == 0) {
#pragma unroll
        for (int u = 0; u < 16; ++u) {
            int ch = (u >> 2) * 16 + quad * 4 + (u & 3);
            sred[wv * 128 + ch]      = s1[u];
            sred[wv * 128 + 64 + ch] = s2[u];
        }
    }
    __syncthreads();
    if (threadIdx.x < 128) {
        float t = sred[threadIdx.x] + sred[128 + threadIdx.x] +
                  sred[256 + threadIdx.x] + sred[384 + threadIdx.x];
        atomicAdd(&statsOut[threadIdx.x], t);
    }
}

// ---------------------------------------------------------------------------
// aggr2[i][:] = bf16( sum over CSR slots of relu(bn2(y2p[k][:])) )
__global__ __launch_bounds__(256) void agg_gather_kernel(
    const short* __restrict__ y2p, const int* __restrict__ off,
    const float* __restrict__ raw, const float* __restrict__ gamma,
    const float* __restrict__ beta, float invc,
    short* __restrict__ aggr2, int N)
{
    const int lane = threadIdx.x & 63;
    const int r    = lane >> 5;
    const int c2   = lane & 31;
    const int c0   = 2 * c2;
    float mu0  = raw[c0] * invc;
    float var0 = fmaf(raw[64 + c0], invc, -mu0 * mu0);
    float sa   = rsqrtf(var0 + BN_EPS) * gamma[c0];
    float ha   = fmaf(-mu0, sa, beta[c0]);
    float mu1  = raw[c0 + 1] * invc;
    float var1 = fmaf(raw[64 + c0 + 1], invc, -mu1 * mu1);
    float sb   = rsqrtf(var1 + BN_EPS) * gamma[c0 + 1];
    float hb   = fmaf(-mu1, sb, beta[c0 + 1]);
    const int wid = (blockIdx.x * blockDim.x + threadIdx.x) >> 6;
    const int nw  = (gridDim.x * blockDim.x) >> 6;
    for (int i = wid; i < N; i += nw) {
        int a = off[i], b = off[i + 1];
        float acc0 = 0.f, acc1 = 0.f;
        int k = a;
        for (; k + 2 <= b; k += 2) {
            unsigned u = __builtin_nontemporal_load(
                (const unsigned*)(y2p + (size_t)(k + r) * 64 + c0));
            acc0 += fmaxf(fmaf(bf2f((short)(u & 0xffff)), sa, ha), 0.f);
            acc1 += fmaxf(fmaf(bf2f((short)(u >> 16)),    sb, hb), 0.f);
        }
        if (k < b && r == 0) {
            unsigned u = __builtin_nontemporal_load(
                (const unsigned*)(y2p + (size_t)k * 64 + c0));
            acc0 += fmaxf(fmaf(bf2f((short)(u & 0xffff)), sa, ha), 0.f);
            acc1 += fmaxf(fmaf(bf2f((short)(u >> 16)),    sb, hb), 0.f);
        }
        acc0 += __shfl_xor(acc0, 32, 64);
        acc1 += __shfl_xor(acc1, 32, 64);
        if (lane < 32)
            *(unsigned*)(aggr2 + (size_t)i * 64 + c0) = pack2(acc0, acc1);
    }
}

// ---------------------------------------------------------------------------
__global__ __launch_bounds__(256) void pred_kernel(
    const short* __restrict__ z2, const float* __restrict__ raw,
    const float* __restrict__ gamma, const float* __restrict__ beta, float invc,
    const float* __restrict__ Wp, const float* __restrict__ bp,
    float* __restrict__ out, int Nn)
{
    const int lane = threadIdx.x & 63;
    float mu  = raw[lane] * invc;
    float var = fmaf(raw[64 + lane], invc, -mu * mu);
    float sc  = rsqrtf(var + BN_EPS) * gamma[lane];
    float sh  = fmaf(-mu, sc, beta[lane]);
    const float wc = Wp[lane];
    const float bb = bp[0];
    const int wid = (blockIdx.x * blockDim.x + threadIdx.x) >> 6;
    const int nw  = (gridDim.x * blockDim.x) >> 6;
    for (int i = wid; i < Nn; i += nw) {
        float v = bf2f(z2[(size_t)i * 64 + lane]);
        float p = fmaxf(fmaf(v, sc, sh), 0.f) * wc;
#pragma unroll
        for (int off = 32; off > 0; off >>= 1) p += __shfl_xor(p, off, 64);
        if (lane == 0) out[i] = p + bb;
    }
}

// ---------------------------------------------------------------------------
extern "C" void kernel_launch(void* const* d_in, const int* in_sizes, int n_in,
                              void* d_out, int out_size, void* d_ws, size_t ws_size,
                              hipStream_t stream)
{
    const float* pos  = (const float*)d_in[0];
    const float* vel  = (const float*)d_in[1];
    const int*   eidx = (const int*)d_in[2];
    const float* W_in = (const float*)d_in[3];
    const float* b_in = (const float*)d_in[4];
    const float* mW1  = (const float*)d_in[5];
    const float* mg1  = (const float*)d_in[7];
    const float* mB1  = (const float*)d_in[8];
    const float* mW2  = (const float*)d_in[9];
    const float* mg2  = (const float*)d_in[11];
    const float* mB2  = (const float*)d_in[12];
    const float* uW1  = (const float*)d_in[13];
    const float* ug1  = (const float*)d_in[15];
    const float* uB1  = (const float*)d_in[16];
    const float* uW2  = (const float*)d_in[17];
    const float* ug2  = (const float*)d_in[19];
    const float* uB2  = (const float*)d_in[20];
    const float* Wp   = (const float*)d_in[21];
    const float* bp   = (const float*)d_in[22];
    // NOTE: mb1/mb2/ub1/ub2 cancel exactly through batch-stat BN.

    const int N = in_sizes[0] / 2;
    const int E = in_sizes[2] / 2;
    const int* src = eidx;       // edge_index[0] = source j
    const int* dst = eidx + E;   // edge_index[1] = dest   i (aggregation target)

    // workspace layout (~244.5 MB — proven r5–r9 footprint)
    float* ws    = (float*)d_ws;
    float* stats = ws;                         // 4 x 128 raw (sum, sumsq)
    int*   cnt   = (int*)(ws + 512);           // N
    int*   off   = cnt + N;                    // N+4
    int*   cur   = off + N + 4;                // N
    int*   bsum  = cur + N;                    // 1024
    short* w1f   = (short*)(bsum + 1024);      // 8192
    short* w2f   = w1f + 8192;                 // 4096
    short* nw1f  = w2f + 4096;                 // 8192
    short* nw2f  = nw1f + 8192;                // 4096
    short* h2    = nw2f + 4096;                // N*64 bf16
    short* aggr2 = h2 + (size_t)N * 64;        // N*64 bf16
    short* z2    = aggr2 + (size_t)N * 64;     // N*64 bf16
    short* y2p   = z2 + (size_t)N * 64;        // E*64 bf16 (CSR slot order)
    float* out   = (float*)d_out;

    const int NB = (N + 1023) / 1024;
    const int FUSE_LDS = 4 * 2048 + 2048;
    const int STAT_LDS = 2048;
    const int TSTEP = 8;
    const int nsamp = ((E >> 4) / TSTEP) << 4;

    hipMemsetAsync(stats, 0, 512 * sizeof(float) + (size_t)N * sizeof(int), stream);

    prep_embed_kernel<<<12 + (N * 64 + 255) / 256, 256, 0, stream>>>(
        mW1, mW2, uW1, uW2, w1f, w2f, nw1f, nw2f,
        pos, vel, W_in, b_in, h2, N);

    hist_stats_kernel<<<1024, 256, 0, stream>>>(
        h2, dst, src, w1f, cnt, stats + 0, E, TSTEP);

    scan1_kernel<<<NB, 256, 0, stream>>>(cnt, off, bsum, N);
    scan2_kernel<<<1, 64, 0, stream>>>(bsum, NB);
    scan3_kernel<<<512, 256, 0, stream>>>(off, cur, bsum, N, E);

    edge_fused_kernel<<<2048, 256, FUSE_LDS, stream>>>(
        h2, dst, src, w1f, w2f, stats + 0, mg1, mB1, 1.0f / (float)nsamp,
        stats + 128, y2p, cur, E);

    agg_gather_kernel<<<2048, 256, 0, stream>>>(
        y2p, off, stats + 128, mg2, mB2, 1.0f / (float)E, aggr2, N);

    node_mfma_kernel<false><<<1024, 256, STAT_LDS, stream>>>(
        h2, aggr2, nw1f, nullptr, nullptr, nullptr, nullptr, 0.f,
        stats + 256, nullptr, N);
    node_mfma_kernel<true><<<1024, 256, FUSE_LDS, stream>>>(
        h2, aggr2, nw1f, nw2f, stats + 256, ug1, uB1, 1.0f / (float)N,
        stats + 384, z2, N);

    pred_kernel<<<512, 256, 0, stream>>>(
        z2, stats + 384, ug2, uB2, 1.0f / (float)N, Wp, bp, out, N);
}